// Round 1
// baseline (2522.881 us; speedup 1.0000x reference)
//
#include <hip/hip_runtime.h>

static constexpr int NBRS = 21;
static constexpr int Bsz  = 4;
static constexpr int Nv   = 12288;
static constexpr int BV   = Bsz * Nv;          // 49152 rows
static constexpr float BN_EPS = 1e-5f;
static constexpr int BN_NB = 128;              // partial-reduce blocks

// ---------------- SPMM: y[b,v,c] = sum_j val[21v+j] * x[b,col[21v+j],c]
// CHEB2 variant: y = 2*L*x - x0
template<bool CHEB2>
__global__ void spmm_kernel(float* __restrict__ y, const float* __restrict__ x,
                            const float* __restrict__ x0,
                            const float* __restrict__ val, const int* __restrict__ col,
                            int C)
{
    int idx = blockIdx.x * 256 + threadIdx.x;
    int c = idx % C;
    int v = (idx / C) % Nv;
    int b = idx / (C * Nv);
    int e0 = v * NBRS;
    float acc = 0.f;
    #pragma unroll
    for (int j = 0; j < NBRS; ++j) {
        int u = col[e0 + j];
        acc += val[e0 + j] * x[((size_t)b * Nv + u) * C + c];
    }
    if (CHEB2) y[idx] = 2.f * acc - x0[idx];
    else       y[idx] = acc;
}

// ---------------- Cheb GEMM: out[m,o] = sum_ki xs[m,ki] * w[ki*FOUT+o] (+bias)
// xs assembled from up to 3 source tensors (T_k(L) x), each [BV, FIN].
// Block: OTHR*RGRP threads; each thread computes RPG rows x TO outputs.
template<int FOUT, int KFIN, int FIN, int TO, int OTHR, int RGRP, int RPG, int NSRC, bool HAS_BIAS>
__global__ __launch_bounds__(OTHR * RGRP)
void cheb_gemm_kernel(const float* __restrict__ x0, const float* __restrict__ x1,
                      const float* __restrict__ x2,
                      const float* __restrict__ w, const float* __restrict__ bias,
                      float* __restrict__ out)
{
    constexpr int THREADS = OTHR * RGRP;
    constexpr int ROWS = RGRP * RPG;
    __shared__ float xs[ROWS][KFIN + 1];
    const int tid = threadIdx.x;
    const int m0 = blockIdx.x * ROWS;

    for (int t = tid; t < ROWS * KFIN; t += THREADS) {
        int r = t / KFIN, ki = t % KFIN;
        const float* src;
        int i;
        if constexpr (NSRC == 1) { src = x0; i = ki; }
        else {
            int k = ki / FIN; i = ki % FIN;
            src = (k == 0) ? x0 : (k == 1 ? x1 : x2);
        }
        xs[r][ki] = src[(size_t)(m0 + r) * FIN + i];
    }
    __syncthreads();

    const int othr = tid % OTHR;
    const int grp  = tid / OTHR;
    const int o0 = othr * TO;
    const int r0 = grp * RPG;

    float acc[RPG][TO];
    #pragma unroll
    for (int r = 0; r < RPG; ++r)
        #pragma unroll
        for (int t = 0; t < TO; ++t) acc[r][t] = 0.f;

    #pragma unroll 4
    for (int ki = 0; ki < KFIN; ++ki) {
        float wv[TO];
        if constexpr (TO == 4) {
            float4 w4 = *reinterpret_cast<const float4*>(w + (size_t)ki * FOUT + o0);
            wv[0] = w4.x; wv[1] = w4.y; wv[2] = w4.z; wv[3] = w4.w;
        } else {
            #pragma unroll
            for (int t = 0; t < TO; ++t) wv[t] = w[(size_t)ki * FOUT + o0 + t];
        }
        #pragma unroll
        for (int r = 0; r < RPG; ++r) {
            float xv = xs[r0 + r][ki];
            #pragma unroll
            for (int t = 0; t < TO; ++t) acc[r][t] += xv * wv[t];
        }
    }

    #pragma unroll
    for (int r = 0; r < RPG; ++r)
        #pragma unroll
        for (int t = 0; t < TO; ++t) {
            float v = acc[r][t];
            if constexpr (HAS_BIAS) v += bias[o0 + t];
            out[(size_t)(m0 + r0 + r) * FOUT + o0 + t] = v;
        }
}

// ---------------- BatchNorm (training stats over B*V per channel), deterministic 2-stage
__global__ void bn_partial_kernel(const float* __restrict__ x, float* __restrict__ partial, int n)
{
    int t = blockIdx.x * 256 + threadIdx.x;
    float s = 0.f, ss = 0.f;
    for (int i = t; i < n; i += BN_NB * 256) { float v = x[i]; s += v; ss += v * v; }
    partial[t * 2] = s; partial[t * 2 + 1] = ss;
}

template<int C>
__global__ void bn_finalize_kernel(const float* __restrict__ partial,
                                   const float* __restrict__ g, const float* __restrict__ b,
                                   float* __restrict__ ab, float invN)
{
    int c = threadIdx.x;
    float s = 0.f, ss = 0.f;
    for (int t = c; t < BN_NB * 256; t += C) { s += partial[t * 2]; ss += partial[t * 2 + 1]; }
    float m = s * invN;
    float var = ss * invN - m * m;
    float a = g[c] * rsqrtf(var + BN_EPS);
    ab[c * 2] = a;
    ab[c * 2 + 1] = b[c] - m * a;
}

template<int C, bool RELU, bool ADD>
__global__ void bn_apply_kernel(float* __restrict__ out, const float* __restrict__ x,
                                const float* __restrict__ base, const float* __restrict__ ab)
{
    int i = blockIdx.x * 256 + threadIdx.x;
    int c = i % C;
    float v = fmaf(x[i], ab[c * 2], ab[c * 2 + 1]);
    if (ADD) v += base[i];
    if (RELU) v = fmaxf(v, 0.f);
    out[i] = v;
}

// ---------------- small elementwise helpers for conv3 (commuted form)
__global__ void combine_kernel(float* __restrict__ e, const float* __restrict__ z1,
                               const float* __restrict__ t)
{
    int i = blockIdx.x * 256 + threadIdx.x;
    e[i] = z1[i] + 2.f * t[i];
}

__global__ void final_add_kernel(float* __restrict__ out, const float* __restrict__ z0,
                                 const float* __restrict__ z2, const float* __restrict__ s)
{
    int i = blockIdx.x * 256 + threadIdx.x;
    out[i] = z0[i] - z2[i] + s[i];
}

extern "C" void kernel_launch(void* const* d_in, const int* in_sizes, int n_in,
                              void* d_out, int out_size, void* d_ws, size_t ws_size,
                              hipStream_t stream)
{
    const float* x       = (const float*)d_in[0];
    const int*   col     = (const int*)  d_in[2];
    const float* eval_   = (const float*)d_in[3];
    const float* conv1_w = (const float*)d_in[4];
    const float* conv1_b = (const float*)d_in[5];
    const float* bn1_g   = (const float*)d_in[6];
    const float* bn1_b   = (const float*)d_in[7];
    const float* conv2_w = (const float*)d_in[8];
    const float* conv2_b = (const float*)d_in[9];
    const float* bn2_g   = (const float*)d_in[10];
    const float* bn2_b   = (const float*)d_in[11];
    const float* bt_c1w  = (const float*)d_in[12];
    const float* bt_c1b  = (const float*)d_in[13];
    const float* bt_c2w  = (const float*)d_in[14];
    const float* bt_c2b  = (const float*)d_in[15];
    const float* bt_c3w  = (const float*)d_in[16];
    const float* bt_c3b  = (const float*)d_in[17];
    const float* btbn1g  = (const float*)d_in[18];
    const float* btbn1b  = (const float*)d_in[19];
    const float* btbn2g  = (const float*)d_in[20];
    const float* btbn2b  = (const float*)d_in[21];
    const float* btbn3g  = (const float*)d_in[22];
    const float* btbn3b  = (const float*)d_in[23];
    const float* conv3_w = (const float*)d_in[24];
    const float* conv3_b = (const float*)d_in[25];
    float* out = (float*)d_out;

    float* ws = (float*)d_ws;
    float* h2      = ws;                         // BV*256
    float* y3      = h2 + (size_t)BV * 256;      // BV*256
    float* t64a    = y3 + (size_t)BV * 256;      // BV*64
    float* t64b    = t64a + (size_t)BV * 64;     // BV*64
    float* t64c    = t64b + (size_t)BV * 64;     // BV*64
    float* t64d    = t64c + (size_t)BV * 64;     // BV*64
    float* partial = t64d + (size_t)BV * 64;     // BN_NB*256*2
    float* ab      = partial + BN_NB * 256 * 2;  // 512

    const float invN = 1.f / (float)BV;

    // ---------- Stage A: conv1 (Fin=8 -> 64), K=3 ----------
    spmm_kernel<false><<<BV * 8 / 256, 256, 0, stream>>>(t64a, x, nullptr, eval_, col, 8);
    spmm_kernel<true ><<<BV * 8 / 256, 256, 0, stream>>>(t64b, t64a, x, eval_, col, 8);
    cheb_gemm_kernel<64, 24, 8, 4, 16, 16, 4, 3, true>
        <<<BV / 64, 256, 0, stream>>>(x, t64a, t64b, conv1_w, conv1_b, t64c);
    bn_partial_kernel<<<BN_NB, 256, 0, stream>>>(t64c, partial, BV * 64);
    bn_finalize_kernel<64><<<1, 64, 0, stream>>>(partial, bn1_g, bn1_b, ab, invN);
    bn_apply_kernel<64, true, false><<<BV * 64 / 256, 256, 0, stream>>>(t64c, t64c, nullptr, ab);

    // ---------- Stage B: conv2 (64 -> 256), K=3 ----------
    spmm_kernel<false><<<BV * 64 / 256, 256, 0, stream>>>(t64a, t64c, nullptr, eval_, col, 64);
    spmm_kernel<true ><<<BV * 64 / 256, 256, 0, stream>>>(t64b, t64a, t64c, eval_, col, 64);
    cheb_gemm_kernel<256, 192, 64, 4, 64, 4, 8, 3, true>
        <<<BV / 32, 256, 0, stream>>>(t64c, t64a, t64b, conv2_w, conv2_b, h2);
    bn_partial_kernel<<<BN_NB, 256, 0, stream>>>(h2, partial, BV * 256);
    bn_finalize_kernel<256><<<1, 256, 0, stream>>>(partial, bn2_g, bn2_b, ab, invN);
    bn_apply_kernel<256, true, false><<<BV * 256 / 256, 256, 0, stream>>>(h2, h2, nullptr, ab);

    // ---------- Stage C: 3 bottlenecks ----------
    for (int i = 0; i < 3; ++i) {
        // cheb1: K=1, 256->64
        cheb_gemm_kernel<64, 256, 256, 4, 16, 16, 2, 1, true>
            <<<BV / 32, 256, 0, stream>>>(h2, nullptr, nullptr,
                                          bt_c1w + (size_t)i * 256 * 64, bt_c1b + i * 64, t64c);
        bn_partial_kernel<<<BN_NB, 256, 0, stream>>>(t64c, partial, BV * 64);
        bn_finalize_kernel<64><<<1, 64, 0, stream>>>(partial, btbn1g + i * 64, btbn1b + i * 64, ab, invN);
        bn_apply_kernel<64, true, false><<<BV * 64 / 256, 256, 0, stream>>>(t64c, t64c, nullptr, ab);

        // cheb2: K=3, 64->64
        spmm_kernel<false><<<BV * 64 / 256, 256, 0, stream>>>(t64a, t64c, nullptr, eval_, col, 64);
        spmm_kernel<true ><<<BV * 64 / 256, 256, 0, stream>>>(t64b, t64a, t64c, eval_, col, 64);
        cheb_gemm_kernel<64, 192, 64, 4, 16, 16, 2, 3, true>
            <<<BV / 32, 256, 0, stream>>>(t64c, t64a, t64b,
                                          bt_c2w + (size_t)i * 3 * 64 * 64, bt_c2b + i * 64, t64d);
        bn_partial_kernel<<<BN_NB, 256, 0, stream>>>(t64d, partial, BV * 64);
        bn_finalize_kernel<64><<<1, 64, 0, stream>>>(partial, btbn2g + i * 64, btbn2b + i * 64, ab, invN);
        bn_apply_kernel<64, true, false><<<BV * 64 / 256, 256, 0, stream>>>(t64d, t64d, nullptr, ab);

        // cheb3: K=1, 64->256, BN (no relu), residual add into h2
        cheb_gemm_kernel<256, 64, 64, 4, 64, 4, 8, 1, true>
            <<<BV / 32, 256, 0, stream>>>(t64d, nullptr, nullptr,
                                          bt_c3w + (size_t)i * 64 * 256, bt_c3b + i * 256, y3);
        bn_partial_kernel<<<BN_NB, 256, 0, stream>>>(y3, partial, BV * 256);
        bn_finalize_kernel<256><<<1, 256, 0, stream>>>(partial, btbn3g + i * 256, btbn3b + i * 256, ab, invN);
        bn_apply_kernel<256, false, true><<<BV * 256 / 256, 256, 0, stream>>>(h2, y3, h2, ab);
    }

    // ---------- Stage D: conv3 (256 -> 8), K=3, commuted: out = z0 - z2 + L(z1 + 2*L*z2) ----------
    float* z0 = t64a;
    float* z1 = z0 + (size_t)BV * 8;
    float* z2 = z1 + (size_t)BV * 8;
    float* tt = z2 + (size_t)BV * 8;
    float* ee = tt + (size_t)BV * 8;
    float* sb = ee + (size_t)BV * 8;

    cheb_gemm_kernel<8, 256, 256, 4, 2, 32, 1, 1, true>
        <<<BV / 32, 64, 0, stream>>>(h2, nullptr, nullptr, conv3_w, conv3_b, z0);
    cheb_gemm_kernel<8, 256, 256, 4, 2, 32, 1, 1, false>
        <<<BV / 32, 64, 0, stream>>>(h2, nullptr, nullptr, conv3_w + 2048, nullptr, z1);
    cheb_gemm_kernel<8, 256, 256, 4, 2, 32, 1, 1, false>
        <<<BV / 32, 64, 0, stream>>>(h2, nullptr, nullptr, conv3_w + 4096, nullptr, z2);

    spmm_kernel<false><<<BV * 8 / 256, 256, 0, stream>>>(tt, z2, nullptr, eval_, col, 8);
    combine_kernel<<<BV * 8 / 256, 256, 0, stream>>>(ee, z1, tt);
    spmm_kernel<false><<<BV * 8 / 256, 256, 0, stream>>>(sb, ee, nullptr, eval_, col, 8);
    final_add_kernel<<<BV * 8 / 256, 256, 0, stream>>>(out, z0, z2, sb);

    (void)in_sizes; (void)n_in; (void)out_size; (void)ws_size;
}

// Round 2
// 1288.379 us; speedup vs baseline: 1.9582x; 1.9582x over previous
//
#include <hip/hip_runtime.h>

static constexpr int NBRS = 21;
static constexpr int Bsz  = 4;
static constexpr int Nv   = 12288;
static constexpr int BV   = Bsz * Nv;          // 49152 rows
static constexpr float BN_EPS = 1e-5f;
static constexpr int BN_NB = 512;              // partial-reduce blocks

// ---------------- SPMM (generic C, scalar): y[b,v,c] = sum_j val[21v+j] * x[b,col,c]
template<bool CHEB2>
__global__ void spmm_kernel(float* __restrict__ y, const float* __restrict__ x,
                            const float* __restrict__ x0,
                            const float* __restrict__ val, const int* __restrict__ col,
                            int C)
{
    int idx = blockIdx.x * 256 + threadIdx.x;
    int c = idx % C;
    int v = (idx / C) % Nv;
    int b = idx / (C * Nv);
    int e0 = v * NBRS;
    float acc = 0.f;
    #pragma unroll
    for (int j = 0; j < NBRS; ++j) {
        int u = col[e0 + j];
        acc += val[e0 + j] * x[((size_t)b * Nv + u) * C + c];
    }
    if (CHEB2) y[idx] = 2.f * acc - x0[idx];
    else       y[idx] = acc;
}

// ---------------- SPMM C=64, float4: 16 threads per row
template<bool CHEB2>
__global__ __launch_bounds__(256)
void spmm64_kernel(float* __restrict__ y, const float* __restrict__ x,
                   const float* __restrict__ x0,
                   const float* __restrict__ val, const int* __restrict__ col)
{
    int idx = blockIdx.x * 256 + threadIdx.x;   // over BV*16
    int q = idx % 16;
    int v = (idx / 16) % Nv;
    int b = idx / (16 * Nv);
    int e0 = v * NBRS;
    const float4* x4 = (const float4*)x;
    float4 acc = {0.f, 0.f, 0.f, 0.f};
    #pragma unroll
    for (int j = 0; j < NBRS; ++j) {
        int u = col[e0 + j];
        float a = val[e0 + j];
        float4 xv = x4[(size_t)(b * Nv + u) * 16 + q];
        acc.x = fmaf(a, xv.x, acc.x);
        acc.y = fmaf(a, xv.y, acc.y);
        acc.z = fmaf(a, xv.z, acc.z);
        acc.w = fmaf(a, xv.w, acc.w);
    }
    if (CHEB2) {
        float4 pv = ((const float4*)x0)[idx];
        acc.x = 2.f * acc.x - pv.x;
        acc.y = 2.f * acc.y - pv.y;
        acc.z = 2.f * acc.z - pv.z;
        acc.w = 2.f * acc.w - pv.w;
    }
    ((float4*)y)[idx] = acc;
}

// ---------------- Cheb GEMM: out[m,o] = sum_ki xs[m,ki] * w[ki*FOUT+o] (+bias)
template<int FOUT, int KFIN, int FIN, int TO, int OTHR, int RGRP, int RPG, int NSRC, bool HAS_BIAS>
__global__ __launch_bounds__(OTHR * RGRP)
void cheb_gemm_kernel(const float* __restrict__ x0, const float* __restrict__ x1,
                      const float* __restrict__ x2,
                      const float* __restrict__ w, const float* __restrict__ bias,
                      float* __restrict__ out)
{
    constexpr int THREADS = OTHR * RGRP;
    constexpr int ROWS = RGRP * RPG;
    __shared__ float xs[ROWS][KFIN + 1];
    const int tid = threadIdx.x;
    const int m0 = blockIdx.x * ROWS;

    for (int t = tid; t < ROWS * KFIN; t += THREADS) {
        int r = t / KFIN, ki = t % KFIN;
        const float* src;
        int i;
        if constexpr (NSRC == 1) { src = x0; i = ki; }
        else {
            int k = ki / FIN; i = ki % FIN;
            src = (k == 0) ? x0 : (k == 1 ? x1 : x2);
        }
        xs[r][ki] = src[(size_t)(m0 + r) * FIN + i];
    }
    __syncthreads();

    const int othr = tid % OTHR;
    const int grp  = tid / OTHR;
    const int o0 = othr * TO;
    const int r0 = grp * RPG;

    float acc[RPG][TO];
    #pragma unroll
    for (int r = 0; r < RPG; ++r)
        #pragma unroll
        for (int t = 0; t < TO; ++t) acc[r][t] = 0.f;

    #pragma unroll 4
    for (int ki = 0; ki < KFIN; ++ki) {
        float wv[TO];
        if constexpr (TO == 4) {
            float4 w4 = *reinterpret_cast<const float4*>(w + (size_t)ki * FOUT + o0);
            wv[0] = w4.x; wv[1] = w4.y; wv[2] = w4.z; wv[3] = w4.w;
        } else {
            #pragma unroll
            for (int t = 0; t < TO; ++t) wv[t] = w[(size_t)ki * FOUT + o0 + t];
        }
        #pragma unroll
        for (int r = 0; r < RPG; ++r) {
            float xv = xs[r0 + r][ki];
            #pragma unroll
            for (int t = 0; t < TO; ++t) acc[r][t] = fmaf(xv, wv[t], acc[r][t]);
        }
    }

    #pragma unroll
    for (int r = 0; r < RPG; ++r)
        #pragma unroll
        for (int t = 0; t < TO; ++t) {
            float v = acc[r][t];
            if constexpr (HAS_BIAS) v += bias[o0 + t];
            out[(size_t)(m0 + r0 + r) * FOUT + o0 + t] = v;
        }
}

// ---------------- BatchNorm: stage 1 — per-block per-channel sums (float4 + LDS reduce)
template<int C>
__global__ __launch_bounds__(256)
void bn_partial_kernel(const float* __restrict__ x, float2* __restrict__ partial, int n4)
{
    __shared__ float2 red[256][4];    // 8 KB
    const float4* x4 = (const float4*)x;
    int t = blockIdx.x * 256 + threadIdx.x;
    float s0=0,s1=0,s2=0,s3=0, q0=0,q1=0,q2=0,q3=0;
    for (int i = t; i < n4; i += BN_NB * 256) {
        float4 v = x4[i];
        s0 += v.x; q0 = fmaf(v.x, v.x, q0);
        s1 += v.y; q1 = fmaf(v.y, v.y, q1);
        s2 += v.z; q2 = fmaf(v.z, v.z, q2);
        s3 += v.w; q3 = fmaf(v.w, v.w, q3);
    }
    red[threadIdx.x][0] = make_float2(s0, q0);
    red[threadIdx.x][1] = make_float2(s1, q1);
    red[threadIdx.x][2] = make_float2(s2, q2);
    red[threadIdx.x][3] = make_float2(s3, q3);
    __syncthreads();
    // slot (tx, j) holds channel (4*tx + j) % C
    if (threadIdx.x < C) {
        int c = threadIdx.x;
        int j = c & 3, tb = c >> 2;
        float rs = 0.f, rq = 0.f;
        #pragma unroll
        for (int k = tb; k < 256; k += C / 4) {
            float2 p = red[k][j];
            rs += p.x; rq += p.y;
        }
        partial[(size_t)blockIdx.x * C + c] = make_float2(rs, rq);
    }
}

// ---------------- BatchNorm: stage 2 — reduce over blocks, produce (a,b) per channel
template<int C>
__global__ __launch_bounds__(1024)
void bn_finalize_kernel(const float2* __restrict__ partial,
                        const float* __restrict__ g, const float* __restrict__ b,
                        float* __restrict__ ab, float invN)
{
    constexpr int G = 1024 / C;   // 16 (C=64) or 4 (C=256)
    int c  = threadIdx.x / G;
    int gg = threadIdx.x % G;
    float s = 0.f, ss = 0.f;
    for (int k = gg; k < BN_NB; k += G) {
        float2 p = partial[(size_t)k * C + c];
        s += p.x; ss += p.y;
    }
    #pragma unroll
    for (int off = G / 2; off > 0; off >>= 1) {
        s  += __shfl_down(s, off);
        ss += __shfl_down(ss, off);
    }
    if (gg == 0) {
        float m = s * invN;
        float var = ss * invN - m * m;
        float a = g[c] * rsqrtf(var + BN_EPS);
        ab[c * 2]     = a;
        ab[c * 2 + 1] = b[c] - m * a;
    }
}

// ---------------- BatchNorm apply (float4, optional residual add + relu)
template<int C, bool RELU, bool ADD>
__global__ __launch_bounds__(256)
void bn_apply_kernel(float* __restrict__ out, const float* __restrict__ x,
                     const float* __restrict__ base, const float* __restrict__ ab)
{
    int i = blockIdx.x * 256 + threadIdx.x;   // float4 index
    float4 v = ((const float4*)x)[i];
    int c0 = (i * 4) % C;
    const float2* ab2 = (const float2*)ab;
    float2 p0 = ab2[c0], p1 = ab2[c0 + 1], p2 = ab2[c0 + 2], p3 = ab2[c0 + 3];
    float4 r;
    r.x = fmaf(v.x, p0.x, p0.y);
    r.y = fmaf(v.y, p1.x, p1.y);
    r.z = fmaf(v.z, p2.x, p2.y);
    r.w = fmaf(v.w, p3.x, p3.y);
    if (ADD) {
        float4 bv = ((const float4*)base)[i];
        r.x += bv.x; r.y += bv.y; r.z += bv.z; r.w += bv.w;
    }
    if (RELU) {
        r.x = fmaxf(r.x, 0.f); r.y = fmaxf(r.y, 0.f);
        r.z = fmaxf(r.z, 0.f); r.w = fmaxf(r.w, 0.f);
    }
    ((float4*)out)[i] = r;
}

// ---------------- small elementwise helpers for conv3 (commuted form)
__global__ void combine_kernel(float* __restrict__ e, const float* __restrict__ z1,
                               const float* __restrict__ t)
{
    int i = blockIdx.x * 256 + threadIdx.x;
    e[i] = z1[i] + 2.f * t[i];
}

__global__ void final_add_kernel(float* __restrict__ out, const float* __restrict__ z0,
                                 const float* __restrict__ z2, const float* __restrict__ s)
{
    int i = blockIdx.x * 256 + threadIdx.x;
    out[i] = z0[i] - z2[i] + s[i];
}

extern "C" void kernel_launch(void* const* d_in, const int* in_sizes, int n_in,
                              void* d_out, int out_size, void* d_ws, size_t ws_size,
                              hipStream_t stream)
{
    const float* x       = (const float*)d_in[0];
    const int*   col     = (const int*)  d_in[2];
    const float* eval_   = (const float*)d_in[3];
    const float* conv1_w = (const float*)d_in[4];
    const float* conv1_b = (const float*)d_in[5];
    const float* bn1_g   = (const float*)d_in[6];
    const float* bn1_b   = (const float*)d_in[7];
    const float* conv2_w = (const float*)d_in[8];
    const float* conv2_b = (const float*)d_in[9];
    const float* bn2_g   = (const float*)d_in[10];
    const float* bn2_b   = (const float*)d_in[11];
    const float* bt_c1w  = (const float*)d_in[12];
    const float* bt_c1b  = (const float*)d_in[13];
    const float* bt_c2w  = (const float*)d_in[14];
    const float* bt_c2b  = (const float*)d_in[15];
    const float* bt_c3w  = (const float*)d_in[16];
    const float* bt_c3b  = (const float*)d_in[17];
    const float* btbn1g  = (const float*)d_in[18];
    const float* btbn1b  = (const float*)d_in[19];
    const float* btbn2g  = (const float*)d_in[20];
    const float* btbn2b  = (const float*)d_in[21];
    const float* btbn3g  = (const float*)d_in[22];
    const float* btbn3b  = (const float*)d_in[23];
    const float* conv3_w = (const float*)d_in[24];
    const float* conv3_b = (const float*)d_in[25];
    float* out = (float*)d_out;

    float* ws = (float*)d_ws;
    float* h2   = ws;                         // BV*256
    float* y3   = h2 + (size_t)BV * 256;      // BV*256
    float* t64a = y3 + (size_t)BV * 256;      // BV*64
    float* t64b = t64a + (size_t)BV * 64;     // BV*64
    float* t64c = t64b + (size_t)BV * 64;     // BV*64
    float* t64d = t64c + (size_t)BV * 64;     // BV*64
    float* ab   = t64d + (size_t)BV * 64;     // 512
    // partial aliases t64a (free during every BN stats phase): 512*256 float2 = 2 MB
    float2* partial = (float2*)t64a;

    const float invN = 1.f / (float)BV;

    // ---------- Stage A: conv1 (Fin=8 -> 64), K=3 ----------
    spmm_kernel<false><<<BV * 8 / 256, 256, 0, stream>>>(t64a, x, nullptr, eval_, col, 8);
    spmm_kernel<true ><<<BV * 8 / 256, 256, 0, stream>>>(t64b, t64a, x, eval_, col, 8);
    cheb_gemm_kernel<64, 24, 8, 4, 16, 16, 4, 3, true>
        <<<BV / 64, 256, 0, stream>>>(x, t64a, t64b, conv1_w, conv1_b, t64c);
    bn_partial_kernel<64><<<BN_NB, 256, 0, stream>>>(t64c, partial, BV * 64 / 4);
    bn_finalize_kernel<64><<<1, 1024, 0, stream>>>(partial, bn1_g, bn1_b, ab, invN);
    bn_apply_kernel<64, true, false><<<BV * 64 / 1024, 256, 0, stream>>>(t64c, t64c, nullptr, ab);

    // ---------- Stage B: conv2 (64 -> 256), K=3 ----------
    spmm64_kernel<false><<<BV * 16 / 256, 256, 0, stream>>>(t64a, t64c, nullptr, eval_, col);
    spmm64_kernel<true ><<<BV * 16 / 256, 256, 0, stream>>>(t64b, t64a, t64c, eval_, col);
    cheb_gemm_kernel<256, 192, 64, 4, 64, 4, 8, 3, true>
        <<<BV / 32, 256, 0, stream>>>(t64c, t64a, t64b, conv2_w, conv2_b, h2);
    bn_partial_kernel<256><<<BN_NB, 256, 0, stream>>>(h2, partial, BV * 256 / 4);
    bn_finalize_kernel<256><<<1, 1024, 0, stream>>>(partial, bn2_g, bn2_b, ab, invN);
    bn_apply_kernel<256, true, false><<<BV * 256 / 1024, 256, 0, stream>>>(h2, h2, nullptr, ab);

    // ---------- Stage C: 3 bottlenecks ----------
    for (int i = 0; i < 3; ++i) {
        // cheb1: K=1, 256->64
        cheb_gemm_kernel<64, 256, 256, 4, 16, 16, 2, 1, true>
            <<<BV / 32, 256, 0, stream>>>(h2, nullptr, nullptr,
                                          bt_c1w + (size_t)i * 256 * 64, bt_c1b + i * 64, t64c);
        bn_partial_kernel<64><<<BN_NB, 256, 0, stream>>>(t64c, partial, BV * 64 / 4);
        bn_finalize_kernel<64><<<1, 1024, 0, stream>>>(partial, btbn1g + i * 64, btbn1b + i * 64, ab, invN);
        bn_apply_kernel<64, true, false><<<BV * 64 / 1024, 256, 0, stream>>>(t64c, t64c, nullptr, ab);

        // cheb2: K=3, 64->64
        spmm64_kernel<false><<<BV * 16 / 256, 256, 0, stream>>>(t64a, t64c, nullptr, eval_, col);
        spmm64_kernel<true ><<<BV * 16 / 256, 256, 0, stream>>>(t64b, t64a, t64c, eval_, col);
        cheb_gemm_kernel<64, 192, 64, 4, 16, 16, 2, 3, true>
            <<<BV / 32, 256, 0, stream>>>(t64c, t64a, t64b,
                                          bt_c2w + (size_t)i * 3 * 64 * 64, bt_c2b + i * 64, t64d);
        bn_partial_kernel<64><<<BN_NB, 256, 0, stream>>>(t64d, partial, BV * 64 / 4);
        bn_finalize_kernel<64><<<1, 1024, 0, stream>>>(partial, btbn2g + i * 64, btbn2b + i * 64, ab, invN);
        bn_apply_kernel<64, true, false><<<BV * 64 / 1024, 256, 0, stream>>>(t64d, t64d, nullptr, ab);

        // cheb3: K=1, 64->256, BN (no relu), residual add into h2
        cheb_gemm_kernel<256, 64, 64, 4, 64, 4, 8, 1, true>
            <<<BV / 32, 256, 0, stream>>>(t64d, nullptr, nullptr,
                                          bt_c3w + (size_t)i * 64 * 256, bt_c3b + i * 256, y3);
        bn_partial_kernel<256><<<BN_NB, 256, 0, stream>>>(y3, partial, BV * 256 / 4);
        bn_finalize_kernel<256><<<1, 1024, 0, stream>>>(partial, btbn3g + i * 256, btbn3b + i * 256, ab, invN);
        bn_apply_kernel<256, false, true><<<BV * 256 / 1024, 256, 0, stream>>>(h2, y3, h2, ab);
    }

    // ---------- Stage D: conv3 (256 -> 8), K=3, commuted: out = z0 - z2 + L(z1 + 2*L*z2) ----------
    float* z0 = t64a;
    float* z1 = z0 + (size_t)BV * 8;
    float* z2 = z1 + (size_t)BV * 8;
    float* tt = z2 + (size_t)BV * 8;
    float* ee = tt + (size_t)BV * 8;
    float* sb = ee + (size_t)BV * 8;

    cheb_gemm_kernel<8, 256, 256, 4, 2, 32, 1, 1, true>
        <<<BV / 32, 64, 0, stream>>>(h2, nullptr, nullptr, conv3_w, conv3_b, z0);
    cheb_gemm_kernel<8, 256, 256, 4, 2, 32, 1, 1, false>
        <<<BV / 32, 64, 0, stream>>>(h2, nullptr, nullptr, conv3_w + 2048, nullptr, z1);
    cheb_gemm_kernel<8, 256, 256, 4, 2, 32, 1, 1, false>
        <<<BV / 32, 64, 0, stream>>>(h2, nullptr, nullptr, conv3_w + 4096, nullptr, z2);

    spmm_kernel<false><<<BV * 8 / 256, 256, 0, stream>>>(tt, z2, nullptr, eval_, col, 8);
    combine_kernel<<<BV * 8 / 256, 256, 0, stream>>>(ee, z1, tt);
    spmm_kernel<false><<<BV * 8 / 256, 256, 0, stream>>>(sb, ee, nullptr, eval_, col, 8);
    final_add_kernel<<<BV * 8 / 256, 256, 0, stream>>>(out, z0, z2, sb);

    (void)in_sizes; (void)n_in; (void)out_size; (void)ws_size;
}